// Round 5
// baseline (142.777 us; speedup 1.0000x reference)
//
#include <hip/hip_runtime.h>
#include <stdint.h>

// B=32, L=128, A=64, C=128, KT=3.  scale = sqrt(190), inv = 1/sqrt(190).
// Linearity: agent_sum(y) = conv(sum_a x) + 64*bias ; time_sum(y) = W0*(S-x127)+W1*S+W2*(S-x0)+128*bias.
// Main conv fuses the whole epilogue and writes out directly (y never materialized).

typedef __attribute__((ext_vector_type(8))) short bf16x8;
typedef __attribute__((ext_vector_type(4))) float f32x4;

__device__ __forceinline__ uint32_t f2bf(float f) {
    union { float f; uint32_t u; } v; v.f = f;
    return (v.u + 0x7FFFu + ((v.u >> 16) & 1u)) >> 16;  // RNE
}
__device__ __forceinline__ float bf2f(uint32_t h) {
    union { uint32_t u; float f; } v; v.u = h << 16; return v.f;
}
__device__ __forceinline__ uint32_t pk2(float lo, float hi) {
    return f2bf(lo) | (f2bf(hi) << 16);
}
__device__ __forceinline__ void gll16(const void* g, void* l) {
    __builtin_amdgcn_global_load_lds((const __attribute__((address_space(1))) void*)g,
                                     (__attribute__((address_space(3))) void*)l, 16, 0, 0);
}

// W fp32 [co][ci][kt] -> Wpack bf16 in MFMA B-fragment order:
// Wpack[((d*4+ks)*8 + nt)*64 + lane][i], ci = ks*32+(lane>>4)*8+i, co = nt*16+(lane&15)
__global__ void wpack_kernel(const float* __restrict__ W, uint16_t* __restrict__ wp) {
    int o = blockIdx.x * 256 + threadIdx.x;   // 192*256 = 49152 exact
    int i = o & 7, lane = (o >> 3) & 63, nt = (o >> 9) & 7, ks = (o >> 12) & 3, d = o >> 14;
    int ci = ks * 32 + (lane >> 4) * 8 + i;
    int co = nt * 16 + (lane & 15);
    wp[o] = (uint16_t)f2bf(W[(co * 128 + ci) * 3 + d]);
}

// x fp32 [b][t][a][c] -> x16 bf16 [b][tp=t+1][a][c] with zero guard rows tp=0,129;
// also Xa16[b][tp][ci] = bf16(sum_a x) (guard rows zero).
__global__ __launch_bounds__(256) void prep_kernel(
    const float* __restrict__ x, uint16_t* __restrict__ x16, uint16_t* __restrict__ xa16)
{
    const int tid = threadIdx.x;
    const int bid = blockIdx.x;               // b*130 + tp
    const int b = bid / 130, tp = bid - b * 130;
    uint16_t* xo = x16 + (size_t)bid * 8192;
    if (tp == 0 || tp == 129) {
        const uint4 z = make_uint4(0, 0, 0, 0);
        #pragma unroll
        for (int k = 0; k < 4; ++k) *(uint4*)(xo + tid * 32 + k * 8) = z;
        if (tid < 16) *(uint4*)(xa16 + (size_t)bid * 128 + tid * 8) = z;
        return;
    }
    const int t = tp - 1;
    const int ci4 = (tid & 31) * 4, ag = tid >> 5;
    const float* xr = x + (size_t)(b * 128 + t) * 8192;
    float4 part = make_float4(0.f, 0.f, 0.f, 0.f);
    #pragma unroll
    for (int r = 0; r < 8; ++r) {
        const int a = ag * 8 + r;
        const float4 v = *(const float4*)(xr + a * 128 + ci4);
        part.x += v.x; part.y += v.y; part.z += v.z; part.w += v.w;
        uint2 p; p.x = pk2(v.x, v.y); p.y = pk2(v.z, v.w);
        *(uint2*)(xo + a * 128 + ci4) = p;
    }
    __shared__ float red[8][128];
    *(float4*)&red[ag][ci4] = part;
    __syncthreads();
    if (tid < 128) {
        float s = 0.f;
        #pragma unroll
        for (int i = 0; i < 8; ++i) s += red[i][tid];
        xa16[(size_t)bid * 128 + tid] = (uint16_t)f2bf(s);
    }
}

// Xt[b][a][ci] = sum_t x (fp32), read from x16 (L3-hot)
__global__ __launch_bounds__(256) void xt_kernel(
    const uint16_t* __restrict__ x16, float* __restrict__ xt)
{
    const int tid = threadIdx.x, bid = blockIdx.x;   // b*64 + a
    const int a = bid & 63, b = bid >> 6;
    const int ci8 = (tid & 15) * 8, tg = tid >> 4;
    const uint16_t* base = x16 + ((size_t)(b * 130 + 1 + tg) * 64 + a) * 128 + ci8;
    float s[8];
    #pragma unroll
    for (int j = 0; j < 8; ++j) s[j] = 0.f;
    #pragma unroll
    for (int r = 0; r < 8; ++r) {
        const uint4 v = *(const uint4*)(base + (size_t)r * 16 * 8192);
        s[0] += bf2f(v.x & 0xFFFFu); s[1] += bf2f(v.x >> 16);
        s[2] += bf2f(v.y & 0xFFFFu); s[3] += bf2f(v.y >> 16);
        s[4] += bf2f(v.z & 0xFFFFu); s[5] += bf2f(v.z >> 16);
        s[6] += bf2f(v.w & 0xFFFFu); s[7] += bf2f(v.w >> 16);
    }
    __shared__ float red[16][128];
    *(float4*)&red[tg][ci8]     = make_float4(s[0], s[1], s[2], s[3]);
    *(float4*)&red[tg][ci8 + 4] = make_float4(s[4], s[5], s[6], s[7]);
    __syncthreads();
    if (tid < 128) {
        float v = 0.f;
        #pragma unroll
        for (int i = 0; i < 16; ++i) v += red[i][tid];
        xt[(size_t)bid * 128 + tid] = v;
    }
}

// asum[b][t][co] = conv(Xa)[t][co] + 64*bias ; one block per b (mini-MFMA over 130-row slab)
__global__ __launch_bounds__(256, 2) void asum_kernel(
    const uint16_t* __restrict__ xa16, const uint16_t* __restrict__ wp,
    const float* __restrict__ bias, float* __restrict__ asum)
{
    __shared__ __align__(16) uint16_t slab[130 * 128];   // 33280 B, granule-swizzled
    const int tid = threadIdx.x, b = blockIdx.x;
    #pragma unroll
    for (int it = 0; it < 9; ++it) {
        const int gg = it * 256 + tid;
        if (gg < 2080) {
            const int row = gg >> 4, sp = gg & 15;
            const int sl = sp ^ (row & 7);
            *(uint4*)(slab + gg * 8) =
                *(const uint4*)(xa16 + (size_t)(b * 130 + row) * 128 + sl * 8);
        }
    }
    __syncthreads();
    const int lane = tid & 63, wid = tid >> 6;
    const int wm = wid >> 1, wn = wid & 1;
    const int lr = lane & 15, lg = lane >> 4;
    f32x4 acc[4][4];
    #pragma unroll
    for (int mi = 0; mi < 4; ++mi)
        #pragma unroll
        for (int ni = 0; ni < 4; ++ni) acc[mi][ni] = (f32x4)0.f;
    #pragma unroll
    for (int g = 0; g < 4; ++g)
        #pragma unroll
        for (int d = 0; d < 3; ++d) {
            bf16x8 bq[4], af[4];
            #pragma unroll
            for (int ni = 0; ni < 4; ++ni)
                bq[ni] = *(const bf16x8*)(wp + (size_t)((((d * 4 + g) * 8) + wn * 4 + ni) * 64 + lane) * 8);
            #pragma unroll
            for (int mi = 0; mi < 4; ++mi) {
                const int row = wm * 64 + mi * 16 + lr + d;
                af[mi] = *(const bf16x8*)(slab + row * 128 + ((g * 4 + lg) ^ (row & 7)) * 8);
            }
            #pragma unroll
            for (int mi = 0; mi < 4; ++mi)
                #pragma unroll
                for (int ni = 0; ni < 4; ++ni)
                    acc[mi][ni] = __builtin_amdgcn_mfma_f32_16x16x32_bf16(af[mi], bq[ni], acc[mi][ni], 0, 0, 0);
        }
    #pragma unroll
    for (int ni = 0; ni < 4; ++ni) {
        const int col = wn * 64 + ni * 16 + lr;
        const float bv = 64.f * bias[col];
        #pragma unroll
        for (int mi = 0; mi < 4; ++mi)
            #pragma unroll
            for (int j = 0; j < 4; ++j) {
                const int t = wm * 64 + mi * 16 + lg * 4 + j;
                asum[((size_t)b * 128 + t) * 128 + col] = acc[mi][ni][j] + bv;
            }
    }
}

// tsum[b][a][co] = sum_d W_d * V_d + 128*bias, V0=S-x127, V1=S, V2=S-x0.  16 blocks x 128 rows.
__global__ __launch_bounds__(256, 2) void tsum_kernel(
    const float* __restrict__ xt, const uint16_t* __restrict__ x16,
    const uint16_t* __restrict__ wp, const float* __restrict__ bias,
    float* __restrict__ tsum)
{
    __shared__ __align__(16) uint16_t slab[128 * 128];   // 32 KB
    const int tid = threadIdx.x, bid = blockIdx.x;       // rows bid*128..+127 of (b*64+a)
    const int lane = tid & 63, wid = tid >> 6;
    const int wm = wid >> 1, wn = wid & 1;
    const int lr = lane & 15, lg = lane >> 4;
    f32x4 acc[4][4];
    #pragma unroll
    for (int mi = 0; mi < 4; ++mi)
        #pragma unroll
        for (int ni = 0; ni < 4; ++ni) acc[mi][ni] = (f32x4)0.f;
    const int r = tid >> 1, h = tid & 1;
    const int grow = bid * 128 + r, sb = grow >> 6, sa = grow & 63;
    #pragma unroll
    for (int d = 0; d < 3; ++d) {
        {
            const float* Sp = xt + (size_t)grow * 128 + h * 64;
            const uint16_t* Ep = x16 + ((size_t)(sb * 130 + (d == 0 ? 128 : 1)) * 64 + sa) * 128 + h * 64;
            #pragma unroll
            for (int k = 0; k < 8; ++k) {
                float4 f0 = *(const float4*)(Sp + k * 8);
                float4 f1 = *(const float4*)(Sp + k * 8 + 4);
                if (d != 1) {
                    const uint4 e = *(const uint4*)(Ep + k * 8);
                    f0.x -= bf2f(e.x & 0xFFFFu); f0.y -= bf2f(e.x >> 16);
                    f0.z -= bf2f(e.y & 0xFFFFu); f0.w -= bf2f(e.y >> 16);
                    f1.x -= bf2f(e.z & 0xFFFFu); f1.y -= bf2f(e.z >> 16);
                    f1.z -= bf2f(e.w & 0xFFFFu); f1.w -= bf2f(e.w >> 16);
                }
                uint4 o;
                o.x = pk2(f0.x, f0.y); o.y = pk2(f0.z, f0.w);
                o.z = pk2(f1.x, f1.y); o.w = pk2(f1.z, f1.w);
                const int sl = h * 8 + k;
                *(uint4*)(slab + r * 128 + (sl ^ (r & 7)) * 8) = o;
            }
        }
        __syncthreads();
        #pragma unroll
        for (int g = 0; g < 4; ++g) {
            bf16x8 bq[4], af[4];
            #pragma unroll
            for (int ni = 0; ni < 4; ++ni)
                bq[ni] = *(const bf16x8*)(wp + (size_t)((((d * 4 + g) * 8) + wn * 4 + ni) * 64 + lane) * 8);
            #pragma unroll
            for (int mi = 0; mi < 4; ++mi) {
                const int row = wm * 64 + mi * 16 + lr;
                af[mi] = *(const bf16x8*)(slab + row * 128 + ((g * 4 + lg) ^ (row & 7)) * 8);
            }
            #pragma unroll
            for (int mi = 0; mi < 4; ++mi)
                #pragma unroll
                for (int ni = 0; ni < 4; ++ni)
                    acc[mi][ni] = __builtin_amdgcn_mfma_f32_16x16x32_bf16(af[mi], bq[ni], acc[mi][ni], 0, 0, 0);
        }
        __syncthreads();
    }
    #pragma unroll
    for (int ni = 0; ni < 4; ++ni) {
        const int col = wn * 64 + ni * 16 + lr;
        const float bv = 128.f * bias[col];
        #pragma unroll
        for (int mi = 0; mi < 4; ++mi)
            #pragma unroll
            for (int j = 0; j < 4; ++j) {
                const int rg = bid * 128 + wm * 64 + mi * 16 + lg * 4 + j;
                tsum[(size_t)rg * 128 + col] = acc[mi][ni][j] + bv;
            }
    }
}

// Fused conv + epilogue: block per (b, t-pair).  Slab 256 rows x 128 ci bf16 (64 KB),
// staged via global_load_lds with granule XOR swizzle; out written directly.
__global__ __launch_bounds__(256, 2) void conv_kernel(
    const uint16_t* __restrict__ x16, const uint16_t* __restrict__ wp,
    const float* __restrict__ bias, const float* __restrict__ asum,
    const float* __restrict__ tsum, float* __restrict__ out)
{
    __shared__ __align__(16) uint16_t slab[256 * 128];   // 64 KB
    const int tid = threadIdx.x, bid = blockIdx.x;       // b*64 + tg
    const int b = bid >> 6, t0 = (bid & 63) * 2;
    const int lane = tid & 63, wid = tid >> 6;
    const int lr = lane & 15, lg = lane >> 4;

    // ---- async stage: wave wid stages rows wid*64..+63 (16 x 1KB gll) ----
    #pragma unroll
    for (int k = 0; k < 16; ++k) {
        const int row = wid * 64 + k * 4 + lg;
        const int sl = lr ^ (row & 7);                   // logical granule for phys slot lr
        const uint16_t* src = x16 +
            ((size_t)((b * 130 + t0 + (row >> 6)) * 64 + (row & 63))) * 128 + sl * 8;
        gll16(src, slab + wid * 8192 + k * 512);
    }
    __syncthreads();

    const int wm = wid >> 1, wn = wid & 1;
    f32x4 acc[4][4];
    #pragma unroll
    for (int mi = 0; mi < 4; ++mi)
        #pragma unroll
        for (int ni = 0; ni < 4; ++ni) acc[mi][ni] = (f32x4)0.f;

    const int sx = lr & 7;
    #pragma unroll
    for (int g = 0; g < 4; ++g)
        #pragma unroll
        for (int d = 0; d < 3; ++d) {
            bf16x8 bq[4], af[4];
            #pragma unroll
            for (int ni = 0; ni < 4; ++ni)
                bq[ni] = *(const bf16x8*)(wp + (size_t)((((d * 4 + g) * 8) + wn * 4 + ni) * 64 + lane) * 8);
            #pragma unroll
            for (int mi = 0; mi < 4; ++mi) {
                const int row = (wm + d) * 64 + mi * 16 + lr;
                af[mi] = *(const bf16x8*)(slab + row * 128 + ((g * 4 + lg) ^ sx) * 8);
            }
            #pragma unroll
            for (int mi = 0; mi < 4; ++mi)
                #pragma unroll
                for (int ni = 0; ni < 4; ++ni)
                    acc[mi][ni] = __builtin_amdgcn_mfma_f32_16x16x32_bf16(af[mi], bq[ni], acc[mi][ni], 0, 0, 0);
        }
    __syncthreads();

    // ---- epilogue A: y = acc + bias -> bf16 bounce in halo rows (0..63, 192..255) ----
    #pragma unroll
    for (int ni = 0; ni < 4; ++ni) {
        const int col = wn * 64 + ni * 16 + lr;
        const float bv = bias[col];
        #pragma unroll
        for (int mi = 0; mi < 4; ++mi)
            #pragma unroll
            for (int j = 0; j < 4; ++j) {
                const int ro = wm * 64 + mi * 16 + lg * 4 + j;
                const int rmap = ro + ((ro & 64) << 1);          // 0..63 or 192..255
                slab[rmap * 128 + (col ^ ((ro & 7) << 3))] = (uint16_t)f2bf(acc[mi][ni][j] + bv);
            }
    }
    __syncthreads();

    // ---- epilogue B: out = relu((asum + tsum - y)*inv + x), coalesced ----
    {
        const float inv = 0.07254762501100116f;
        const int cg = tid & 15, rb = tid >> 4;
        #pragma unroll
        for (int j = 0; j < 8; ++j) {
            const int ro = j * 16 + rb;
            const int t = t0 + (ro >> 6), a = ro & 63;
            const int rmap = ro + ((ro & 64) << 1);
            const uint4 yv = *(const uint4*)(slab + rmap * 128 + ((cg * 8) ^ ((ro & 7) << 3)));
            const uint4 xv = *(const uint4*)(slab + (ro + 64) * 128 + (cg ^ (ro & 7)) * 8);
            const float* ap = asum + ((size_t)(b * 128 + t)) * 128 + cg * 8;
            const float* tp = tsum + ((size_t)(b * 64 + a)) * 128 + cg * 8;
            const float4 as0 = *(const float4*)ap, as1 = *(const float4*)(ap + 4);
            const float4 ts0 = *(const float4*)tp, ts1 = *(const float4*)(tp + 4);
            float yy[8], xx[8];
            yy[0] = bf2f(yv.x & 0xFFFFu); yy[1] = bf2f(yv.x >> 16);
            yy[2] = bf2f(yv.y & 0xFFFFu); yy[3] = bf2f(yv.y >> 16);
            yy[4] = bf2f(yv.z & 0xFFFFu); yy[5] = bf2f(yv.z >> 16);
            yy[6] = bf2f(yv.w & 0xFFFFu); yy[7] = bf2f(yv.w >> 16);
            xx[0] = bf2f(xv.x & 0xFFFFu); xx[1] = bf2f(xv.x >> 16);
            xx[2] = bf2f(xv.y & 0xFFFFu); xx[3] = bf2f(xv.y >> 16);
            xx[4] = bf2f(xv.z & 0xFFFFu); xx[5] = bf2f(xv.z >> 16);
            xx[6] = bf2f(xv.w & 0xFFFFu); xx[7] = bf2f(xv.w >> 16);
            const float av[8] = {as0.x, as0.y, as0.z, as0.w, as1.x, as1.y, as1.z, as1.w};
            const float tv[8] = {ts0.x, ts0.y, ts0.z, ts0.w, ts1.x, ts1.y, ts1.z, ts1.w};
            float o[8];
            #pragma unroll
            for (int i = 0; i < 8; ++i) {
                const float gg = (av[i] + tv[i] - yy[i]) * inv + xx[i];
                o[i] = gg > 0.f ? gg : 0.f;
            }
            float* op = out + ((size_t)((b * 128 + t) * 64 + a)) * 128 + cg * 8;
            *(float4*)op       = make_float4(o[0], o[1], o[2], o[3]);
            *(float4*)(op + 4) = make_float4(o[4], o[5], o[6], o[7]);
        }
    }
}

extern "C" void kernel_launch(void* const* d_in, const int* in_sizes, int n_in,
                              void* d_out, int out_size, void* d_ws, size_t ws_size,
                              hipStream_t stream) {
    const float* x    = (const float*)d_in[0];
    const float* W    = (const float*)d_in[1];
    const float* bias = (const float*)d_in[2];
    float* out = (float*)d_out;

    // ws layout (73.5 MB):
    //   x16  [32][130][64][128] bf16 : 68,157,440
    //   wp   49152 bf16              :     98,304
    //   xa16 [32][130][128] bf16     :  1,064,960
    //   xt   [32][64][128] f32       :  1,048,576
    //   asum [32][128][128] f32      :  2,097,152
    //   tsum [32][64][128] f32       :  1,048,576
    char* ws = (char*)d_ws;
    uint16_t* x16  = (uint16_t*)(ws);
    uint16_t* wp   = (uint16_t*)(ws + 68157440);
    uint16_t* xa16 = (uint16_t*)(ws + 68157440 + 98304);
    float* xt      = (float*)(ws + 68157440 + 98304 + 1064960);
    float* asum    = (float*)(ws + 68157440 + 98304 + 1064960 + 1048576);
    float* tsum    = (float*)(ws + 68157440 + 98304 + 1064960 + 1048576 + 2097152);

    wpack_kernel<<<192,  256, 0, stream>>>(W, wp);
    prep_kernel <<<4160, 256, 0, stream>>>(x, x16, xa16);
    xt_kernel   <<<2048, 256, 0, stream>>>(x16, xt);
    asum_kernel <<<32,   256, 0, stream>>>(xa16, wp, bias, asum);
    tsum_kernel <<<16,   256, 0, stream>>>(xt, x16, wp, bias, tsum);
    conv_kernel <<<2048, 256, 0, stream>>>(x16, wp, bias, asum, tsum, out);
}

// Round 6
// 131.093 us; speedup vs baseline: 1.0891x; 1.0891x over previous
//
#include <hip/hip_runtime.h>
#include <stdint.h>

// B=32, L=128, A=64, C=128, KT=3.  scale = sqrt(190), inv = 1/sqrt(190).
// Linearity: agent_sum(y) = conv(sum_a x) + 64*bias ; time_sum(y) = W0*(S-x127)+W1*S+W2*(S-x0)+128*bias.
// Main conv fuses the whole epilogue and writes out directly (y never materialized).

typedef __attribute__((ext_vector_type(8))) short bf16x8;
typedef __attribute__((ext_vector_type(4))) float f32x4;

__device__ __forceinline__ uint32_t f2bf(float f) {
    union { float f; uint32_t u; } v; v.f = f;
    return (v.u + 0x7FFFu + ((v.u >> 16) & 1u)) >> 16;  // RNE
}
__device__ __forceinline__ float bf2f(uint32_t h) {
    union { uint32_t u; float f; } v; v.u = h << 16; return v.f;
}
__device__ __forceinline__ uint32_t pk2(float lo, float hi) {
    return f2bf(lo) | (f2bf(hi) << 16);
}
__device__ __forceinline__ void gll16(const void* g, void* l) {
    __builtin_amdgcn_global_load_lds((const __attribute__((address_space(1))) void*)g,
                                     (__attribute__((address_space(3))) void*)l, 16, 0, 0);
}

// prep: x fp32 [b][t][a][c] -> x16 bf16 [b][tp=t+1][a][c] (zero guards tp=0,129) + xa16 = bf16(sum_a x).
// Blocks >= 4160 instead pack W: Wpack[((d*4+ks)*8 + nt)*64 + lane][i],
//   ci = ks*32+(lane>>4)*8+i, co = nt*16+(lane&15)
__global__ __launch_bounds__(256) void prep_kernel(
    const float* __restrict__ x, uint16_t* __restrict__ x16, uint16_t* __restrict__ xa16,
    const float* __restrict__ W, uint16_t* __restrict__ wp)
{
    const int tid = threadIdx.x;
    const int bid = blockIdx.x;
    if (bid >= 4160) {                       // wpack: 192 blocks
        int o = (bid - 4160) * 256 + tid;    // 49152 exact
        int i = o & 7, lane = (o >> 3) & 63, nt = (o >> 9) & 7, ks = (o >> 12) & 3, d = o >> 14;
        int ci = ks * 32 + (lane >> 4) * 8 + i;
        int co = nt * 16 + (lane & 15);
        wp[o] = (uint16_t)f2bf(W[(co * 128 + ci) * 3 + d]);
        return;
    }
    const int b = bid / 130, tp = bid - b * 130;   // b*130 + tp
    uint16_t* xo = x16 + (size_t)bid * 8192;
    if (tp == 0 || tp == 129) {
        const uint4 z = make_uint4(0, 0, 0, 0);
        #pragma unroll
        for (int k = 0; k < 4; ++k) *(uint4*)(xo + tid * 32 + k * 8) = z;
        if (tid < 16) *(uint4*)(xa16 + (size_t)bid * 128 + tid * 8) = z;
        return;
    }
    const int t = tp - 1;
    const int ci4 = (tid & 31) * 4, ag = tid >> 5;
    const float* xr = x + (size_t)(b * 128 + t) * 8192;
    float4 part = make_float4(0.f, 0.f, 0.f, 0.f);
    #pragma unroll
    for (int r = 0; r < 8; ++r) {
        const int a = ag * 8 + r;
        const float4 v = *(const float4*)(xr + a * 128 + ci4);
        part.x += v.x; part.y += v.y; part.z += v.z; part.w += v.w;
        uint2 p; p.x = pk2(v.x, v.y); p.y = pk2(v.z, v.w);
        *(uint2*)(xo + a * 128 + ci4) = p;
    }
    __shared__ float red[8][128];
    *(float4*)&red[ag][ci4] = part;
    __syncthreads();
    if (tid < 128) {
        float s = 0.f;
        #pragma unroll
        for (int i = 0; i < 8; ++i) s += red[i][tid];
        xa16[(size_t)bid * 128 + tid] = (uint16_t)f2bf(s);
    }
}

// Xt[b][a][ci] = sum_t x (fp32), read from x16 (L2/L3-hot)
__global__ __launch_bounds__(256) void xt_kernel(
    const uint16_t* __restrict__ x16, float* __restrict__ xt)
{
    const int tid = threadIdx.x, bid = blockIdx.x;   // b*64 + a
    const int a = bid & 63, b = bid >> 6;
    const int ci8 = (tid & 15) * 8, tg = tid >> 4;
    const uint16_t* base = x16 + ((size_t)(b * 130 + 1 + tg) * 64 + a) * 128 + ci8;
    float s[8];
    #pragma unroll
    for (int j = 0; j < 8; ++j) s[j] = 0.f;
    #pragma unroll
    for (int r = 0; r < 8; ++r) {
        const uint4 v = *(const uint4*)(base + (size_t)r * 16 * 8192);
        s[0] += bf2f(v.x & 0xFFFFu); s[1] += bf2f(v.x >> 16);
        s[2] += bf2f(v.y & 0xFFFFu); s[3] += bf2f(v.y >> 16);
        s[4] += bf2f(v.z & 0xFFFFu); s[5] += bf2f(v.z >> 16);
        s[6] += bf2f(v.w & 0xFFFFu); s[7] += bf2f(v.w >> 16);
    }
    __shared__ float red[16][128];
    *(float4*)&red[tg][ci8]     = make_float4(s[0], s[1], s[2], s[3]);
    *(float4*)&red[tg][ci8 + 4] = make_float4(s[4], s[5], s[6], s[7]);
    __syncthreads();
    if (tid < 128) {
        float v = 0.f;
        #pragma unroll
        for (int i = 0; i < 16; ++i) v += red[i][tid];
        xt[(size_t)bid * 128 + tid] = v;
    }
}

// Combined small-GEMM kernel: blocks 0..31 -> asum (per b), blocks 32..47 -> tsum (128 rows each).
__global__ __launch_bounds__(256, 2) void sums_kernel(
    const uint16_t* __restrict__ xa16, const float* __restrict__ xt,
    const uint16_t* __restrict__ x16, const uint16_t* __restrict__ wp,
    const float* __restrict__ bias, float* __restrict__ asum, float* __restrict__ tsum)
{
    __shared__ __align__(16) uint16_t slab[130 * 128];   // 33280 B (shared by both paths)
    const int tid = threadIdx.x;
    const int lane = tid & 63, wid = tid >> 6;
    const int wm = wid >> 1, wn = wid & 1;
    const int lr = lane & 15, lg = lane >> 4;
    f32x4 acc[4][4];
    #pragma unroll
    for (int mi = 0; mi < 4; ++mi)
        #pragma unroll
        for (int ni = 0; ni < 4; ++ni) acc[mi][ni] = (f32x4)0.f;

    if (blockIdx.x < 32) {
        // ---- asum[b][t][co] = conv(Xa)[t][co] + 64*bias ----
        const int b = blockIdx.x;
        #pragma unroll
        for (int it = 0; it < 9; ++it) {
            const int gg = it * 256 + tid;
            if (gg < 2080) {
                const int row = gg >> 4, sp = gg & 15;
                const int sl = sp ^ (row & 7);
                *(uint4*)(slab + gg * 8) =
                    *(const uint4*)(xa16 + (size_t)(b * 130 + row) * 128 + sl * 8);
            }
        }
        __syncthreads();
        #pragma unroll
        for (int g = 0; g < 4; ++g)
            #pragma unroll
            for (int d = 0; d < 3; ++d) {
                bf16x8 bq[4], af[4];
                #pragma unroll
                for (int ni = 0; ni < 4; ++ni)
                    bq[ni] = *(const bf16x8*)(wp + (size_t)((((d * 4 + g) * 8) + wn * 4 + ni) * 64 + lane) * 8);
                #pragma unroll
                for (int mi = 0; mi < 4; ++mi) {
                    const int row = wm * 64 + mi * 16 + lr + d;
                    af[mi] = *(const bf16x8*)(slab + row * 128 + ((g * 4 + lg) ^ (row & 7)) * 8);
                }
                #pragma unroll
                for (int mi = 0; mi < 4; ++mi)
                    #pragma unroll
                    for (int ni = 0; ni < 4; ++ni)
                        acc[mi][ni] = __builtin_amdgcn_mfma_f32_16x16x32_bf16(af[mi], bq[ni], acc[mi][ni], 0, 0, 0);
            }
        #pragma unroll
        for (int ni = 0; ni < 4; ++ni) {
            const int col = wn * 64 + ni * 16 + lr;
            const float bv = 64.f * bias[col];
            #pragma unroll
            for (int mi = 0; mi < 4; ++mi)
                #pragma unroll
                for (int j = 0; j < 4; ++j) {
                    const int t = wm * 64 + mi * 16 + lg * 4 + j;
                    asum[((size_t)b * 128 + t) * 128 + col] = acc[mi][ni][j] + bv;
                }
        }
        return;
    }

    // ---- tsum[b][a][co] = sum_d W_d * V_d + 128*bias, V0=S-x127, V1=S, V2=S-x0 ----
    const int bid = blockIdx.x - 32;            // rows bid*128..+127 of (b*64+a)
    const int r = tid >> 1, h = tid & 1;
    const int grow = bid * 128 + r, sb = grow >> 6, sa = grow & 63;
    #pragma unroll
    for (int d = 0; d < 3; ++d) {
        {
            const float* Sp = xt + (size_t)grow * 128 + h * 64;
            const uint16_t* Ep = x16 + ((size_t)(sb * 130 + (d == 0 ? 128 : 1)) * 64 + sa) * 128 + h * 64;
            #pragma unroll
            for (int k = 0; k < 8; ++k) {
                float4 f0 = *(const float4*)(Sp + k * 8);
                float4 f1 = *(const float4*)(Sp + k * 8 + 4);
                if (d != 1) {
                    const uint4 e = *(const uint4*)(Ep + k * 8);
                    f0.x -= bf2f(e.x & 0xFFFFu); f0.y -= bf2f(e.x >> 16);
                    f0.z -= bf2f(e.y & 0xFFFFu); f0.w -= bf2f(e.y >> 16);
                    f1.x -= bf2f(e.z & 0xFFFFu); f1.y -= bf2f(e.z >> 16);
                    f1.z -= bf2f(e.w & 0xFFFFu); f1.w -= bf2f(e.w >> 16);
                }
                uint4 o;
                o.x = pk2(f0.x, f0.y); o.y = pk2(f0.z, f0.w);
                o.z = pk2(f1.x, f1.y); o.w = pk2(f1.z, f1.w);
                const int sl = h * 8 + k;
                *(uint4*)(slab + r * 128 + (sl ^ (r & 7)) * 8) = o;
            }
        }
        __syncthreads();
        #pragma unroll
        for (int g = 0; g < 4; ++g) {
            bf16x8 bq[4], af[4];
            #pragma unroll
            for (int ni = 0; ni < 4; ++ni)
                bq[ni] = *(const bf16x8*)(wp + (size_t)((((d * 4 + g) * 8) + wn * 4 + ni) * 64 + lane) * 8);
            #pragma unroll
            for (int mi = 0; mi < 4; ++mi) {
                const int row = wm * 64 + mi * 16 + lr;
                af[mi] = *(const bf16x8*)(slab + row * 128 + ((g * 4 + lg) ^ (row & 7)) * 8);
            }
            #pragma unroll
            for (int mi = 0; mi < 4; ++mi)
                #pragma unroll
                for (int ni = 0; ni < 4; ++ni)
                    acc[mi][ni] = __builtin_amdgcn_mfma_f32_16x16x32_bf16(af[mi], bq[ni], acc[mi][ni], 0, 0, 0);
        }
        __syncthreads();
    }
    #pragma unroll
    for (int ni = 0; ni < 4; ++ni) {
        const int col = wn * 64 + ni * 16 + lr;
        const float bv = 128.f * bias[col];
        #pragma unroll
        for (int mi = 0; mi < 4; ++mi)
            #pragma unroll
            for (int j = 0; j < 4; ++j) {
                const int rg = bid * 128 + wm * 64 + mi * 16 + lg * 4 + j;
                tsum[(size_t)rg * 128 + col] = acc[mi][ni][j] + bv;
            }
    }
}

// Fused conv + epilogue: block per (b, t-pair), 512 threads / 8 waves (2m x 4n).
// Slab 256 rows x 128 ci bf16 (64 KB) via global_load_lds, granule XOR swizzle.
__global__ __launch_bounds__(512, 4) void conv_kernel(
    const uint16_t* __restrict__ x16, const uint16_t* __restrict__ wp,
    const float* __restrict__ bias, const float* __restrict__ asum,
    const float* __restrict__ tsum, float* __restrict__ out)
{
    __shared__ __align__(16) uint16_t slab[256 * 128];   // 64 KB
    const int tid = threadIdx.x, bid = blockIdx.x;       // b*64 + tg
    const int b = bid >> 6, t0 = (bid & 63) * 2;
    const int lane = tid & 63, wid = tid >> 6;           // wid 0..7
    const int lr = lane & 15, lg = lane >> 4;

    // ---- async stage: wave wid stages rows wid*32..+31 (8 x 1KB gll) ----
    #pragma unroll
    for (int k = 0; k < 8; ++k) {
        const int row = wid * 32 + k * 4 + lg;
        const int sl = lr ^ (row & 7);                   // logical granule for phys slot lr
        const uint16_t* src = x16 +
            ((size_t)((b * 130 + t0 + (row >> 6)) * 64 + (row & 63))) * 128 + sl * 8;
        gll16(src, slab + wid * 4096 + k * 512);
    }
    __syncthreads();

    const int wm = wid >> 2, wn = wid & 3;               // 2m x 4n wave grid
    f32x4 acc[4][2];
    #pragma unroll
    for (int mi = 0; mi < 4; ++mi)
        #pragma unroll
        for (int ni = 0; ni < 2; ++ni) acc[mi][ni] = (f32x4)0.f;

    const int sx = lr & 7;
    #pragma unroll
    for (int g = 0; g < 4; ++g)
        #pragma unroll
        for (int d = 0; d < 3; ++d) {
            bf16x8 bq[2], af[4];
            #pragma unroll
            for (int ni = 0; ni < 2; ++ni)
                bq[ni] = *(const bf16x8*)(wp + (size_t)((((d * 4 + g) * 8) + wn * 2 + ni) * 64 + lane) * 8);
            #pragma unroll
            for (int mi = 0; mi < 4; ++mi) {
                const int row = (wm + d) * 64 + mi * 16 + lr;
                af[mi] = *(const bf16x8*)(slab + row * 128 + ((g * 4 + lg) ^ sx) * 8);
            }
            #pragma unroll
            for (int mi = 0; mi < 4; ++mi)
                #pragma unroll
                for (int ni = 0; ni < 2; ++ni)
                    acc[mi][ni] = __builtin_amdgcn_mfma_f32_16x16x32_bf16(af[mi], bq[ni], acc[mi][ni], 0, 0, 0);
        }
    __syncthreads();

    // ---- epilogue A: y = acc + bias -> bf16 bounce in halo rows (0..63, 192..255) ----
    #pragma unroll
    for (int ni = 0; ni < 2; ++ni) {
        const int col = wn * 32 + ni * 16 + lr;
        const float bv = bias[col];
        #pragma unroll
        for (int mi = 0; mi < 4; ++mi)
            #pragma unroll
            for (int j = 0; j < 4; ++j) {
                const int ro = wm * 64 + mi * 16 + lg * 4 + j;
                const int rmap = ro + ((ro & 64) << 1);          // 0..63 or 192..255
                slab[rmap * 128 + (col ^ ((ro & 7) << 3))] = (uint16_t)f2bf(acc[mi][ni][j] + bv);
            }
    }
    __syncthreads();

    // ---- epilogue B: out = relu((asum + tsum - y)*inv + x), coalesced ----
    {
        const float inv = 0.07254762501100116f;
        const int cg = tid & 15, rb = tid >> 4;              // rb 0..31
        #pragma unroll
        for (int j = 0; j < 4; ++j) {
            const int ro = j * 32 + rb;
            const int t = t0 + (ro >> 6), a = ro & 63;
            const int rmap = ro + ((ro & 64) << 1);
            const uint4 yv = *(const uint4*)(slab + rmap * 128 + ((cg * 8) ^ ((ro & 7) << 3)));
            const uint4 xv = *(const uint4*)(slab + (ro + 64) * 128 + (cg ^ (ro & 7)) * 8);
            const float* ap = asum + ((size_t)(b * 128 + t)) * 128 + cg * 8;
            const float* tp = tsum + ((size_t)(b * 64 + a)) * 128 + cg * 8;
            const float4 as0 = *(const float4*)ap, as1 = *(const float4*)(ap + 4);
            const float4 ts0 = *(const float4*)tp, ts1 = *(const float4*)(tp + 4);
            float yy[8], xx[8];
            yy[0] = bf2f(yv.x & 0xFFFFu); yy[1] = bf2f(yv.x >> 16);
            yy[2] = bf2f(yv.y & 0xFFFFu); yy[3] = bf2f(yv.y >> 16);
            yy[4] = bf2f(yv.z & 0xFFFFu); yy[5] = bf2f(yv.z >> 16);
            yy[6] = bf2f(yv.w & 0xFFFFu); yy[7] = bf2f(yv.w >> 16);
            xx[0] = bf2f(xv.x & 0xFFFFu); xx[1] = bf2f(xv.x >> 16);
            xx[2] = bf2f(xv.y & 0xFFFFu); xx[3] = bf2f(xv.y >> 16);
            xx[4] = bf2f(xv.z & 0xFFFFu); xx[5] = bf2f(xv.z >> 16);
            xx[6] = bf2f(xv.w & 0xFFFFu); xx[7] = bf2f(xv.w >> 16);
            const float av[8] = {as0.x, as0.y, as0.z, as0.w, as1.x, as1.y, as1.z, as1.w};
            const float tv[8] = {ts0.x, ts0.y, ts0.z, ts0.w, ts1.x, ts1.y, ts1.z, ts1.w};
            float o[8];
            #pragma unroll
            for (int i = 0; i < 8; ++i) {
                const float gg = (av[i] + tv[i] - yy[i]) * inv + xx[i];
                o[i] = gg > 0.f ? gg : 0.f;
            }
            float* op = out + ((size_t)((b * 128 + t) * 64 + a)) * 128 + cg * 8;
            *(float4*)op       = make_float4(o[0], o[1], o[2], o[3]);
            *(float4*)(op + 4) = make_float4(o[4], o[5], o[6], o[7]);
        }
    }
}

extern "C" void kernel_launch(void* const* d_in, const int* in_sizes, int n_in,
                              void* d_out, int out_size, void* d_ws, size_t ws_size,
                              hipStream_t stream) {
    const float* x    = (const float*)d_in[0];
    const float* W    = (const float*)d_in[1];
    const float* bias = (const float*)d_in[2];
    float* out = (float*)d_out;

    // ws layout (73.5 MB):
    //   x16  [32][130][64][128] bf16 : 68,157,440
    //   wp   49152 bf16              :     98,304
    //   xa16 [32][130][128] bf16     :  1,064,960
    //   xt   [32][64][128] f32       :  1,048,576
    //   asum [32][128][128] f32      :  2,097,152
    //   tsum [32][64][128] f32       :  1,048,576
    char* ws = (char*)d_ws;
    uint16_t* x16  = (uint16_t*)(ws);
    uint16_t* wp   = (uint16_t*)(ws + 68157440);
    uint16_t* xa16 = (uint16_t*)(ws + 68157440 + 98304);
    float* xt      = (float*)(ws + 68157440 + 98304 + 1064960);
    float* asum    = (float*)(ws + 68157440 + 98304 + 1064960 + 1048576);
    float* tsum    = (float*)(ws + 68157440 + 98304 + 1064960 + 1048576 + 2097152);

    prep_kernel <<<4352, 256, 0, stream>>>(x, x16, xa16, W, wp);   // prep + fused wpack
    xt_kernel   <<<2048, 256, 0, stream>>>(x16, xt);
    sums_kernel <<<48,   256, 0, stream>>>(xa16, xt, x16, wp, bias, asum, tsum);
    conv_kernel <<<2048, 512, 0, stream>>>(x16, wp, bias, asum, tsum, out);
}

// Round 8
// 117.721 us; speedup vs baseline: 1.2128x; 1.1136x over previous
//
#include <hip/hip_runtime.h>
#include <stdint.h>

// B=32, L=128, A=64, C=128, KT=3.  scale = sqrt(190), inv = 1/sqrt(190).
// Linearity: agent_sum(y) = conv(sum_a x) + 64*bias ; time_sum(y) = W0*(S-x127)+W1*S+W2*(S-x0)+128*bias.
// Main conv fuses the whole epilogue and writes out directly (y never materialized).

typedef __attribute__((ext_vector_type(8))) short bf16x8;
typedef __attribute__((ext_vector_type(4))) float f32x4;

__device__ __forceinline__ uint32_t f2bf(float f) {
    union { float f; uint32_t u; } v; v.f = f;
    return (v.u + 0x7FFFu + ((v.u >> 16) & 1u)) >> 16;  // RNE
}
__device__ __forceinline__ float bf2f(uint32_t h) {
    union { uint32_t u; float f; } v; v.u = h << 16; return v.f;
}
__device__ __forceinline__ uint32_t pk2(float lo, float hi) {
    return f2bf(lo) | (f2bf(hi) << 16);
}
__device__ __forceinline__ void gll16(const void* g, void* l) {
    __builtin_amdgcn_global_load_lds((const __attribute__((address_space(1))) void*)g,
                                     (__attribute__((address_space(3))) void*)l, 16, 0, 0);
}

// prep: x fp32 [b][t][a][c] -> x16 bf16 [b][tp=t+1][a][c] (zero guards tp=0,129) + xa16 = bf16(sum_a x).
// Blocks >= 4160 instead pack W: Wpack[((d*4+ks)*8 + nt)*64 + lane][i],
//   ci = ks*32+(lane>>4)*8+i, co = nt*16+(lane&15)
__global__ __launch_bounds__(256) void prep_kernel(
    const float* __restrict__ x, uint16_t* __restrict__ x16, uint16_t* __restrict__ xa16,
    const float* __restrict__ W, uint16_t* __restrict__ wp)
{
    const int tid = threadIdx.x;
    const int bid = blockIdx.x;
    if (bid >= 4160) {                       // wpack: 192 blocks
        int o = (bid - 4160) * 256 + tid;    // 49152 exact
        int i = o & 7, lane = (o >> 3) & 63, nt = (o >> 9) & 7, ks = (o >> 12) & 3, d = o >> 14;
        int ci = ks * 32 + (lane >> 4) * 8 + i;
        int co = nt * 16 + (lane & 15);
        wp[o] = (uint16_t)f2bf(W[(co * 128 + ci) * 3 + d]);
        return;
    }
    const int b = bid / 130, tp = bid - b * 130;   // b*130 + tp
    uint16_t* xo = x16 + (size_t)bid * 8192;
    if (tp == 0 || tp == 129) {
        const uint4 z = make_uint4(0, 0, 0, 0);
        #pragma unroll
        for (int k = 0; k < 4; ++k) *(uint4*)(xo + tid * 32 + k * 8) = z;
        if (tid < 16) *(uint4*)(xa16 + (size_t)bid * 128 + tid * 8) = z;
        return;
    }
    const int t = tp - 1;
    const int ci4 = (tid & 31) * 4, ag = tid >> 5;
    const float* xr = x + (size_t)(b * 128 + t) * 8192;
    float4 part = make_float4(0.f, 0.f, 0.f, 0.f);
    #pragma unroll
    for (int r = 0; r < 8; ++r) {
        const int a = ag * 8 + r;
        const float4 v = *(const float4*)(xr + a * 128 + ci4);
        part.x += v.x; part.y += v.y; part.z += v.z; part.w += v.w;
        uint2 p; p.x = pk2(v.x, v.y); p.y = pk2(v.z, v.w);
        *(uint2*)(xo + a * 128 + ci4) = p;
    }
    __shared__ float red[8][128];
    *(float4*)&red[ag][ci4] = part;
    __syncthreads();
    if (tid < 128) {
        float s = 0.f;
        #pragma unroll
        for (int i = 0; i < 8; ++i) s += red[i][tid];
        xa16[(size_t)bid * 128 + tid] = (uint16_t)f2bf(s);
    }
}

// Xt[b][a][ci] = sum_t x (fp32), read from x16 (L2/L3-hot)
__global__ __launch_bounds__(256) void xt_kernel(
    const uint16_t* __restrict__ x16, float* __restrict__ xt)
{
    const int tid = threadIdx.x, bid = blockIdx.x;   // b*64 + a
    const int a = bid & 63, b = bid >> 6;
    const int ci8 = (tid & 15) * 8, tg = tid >> 4;
    const uint16_t* base = x16 + ((size_t)(b * 130 + 1 + tg) * 64 + a) * 128 + ci8;
    float s[8];
    #pragma unroll
    for (int j = 0; j < 8; ++j) s[j] = 0.f;
    #pragma unroll
    for (int r = 0; r < 8; ++r) {
        const uint4 v = *(const uint4*)(base + (size_t)r * 16 * 8192);
        s[0] += bf2f(v.x & 0xFFFFu); s[1] += bf2f(v.x >> 16);
        s[2] += bf2f(v.y & 0xFFFFu); s[3] += bf2f(v.y >> 16);
        s[4] += bf2f(v.z & 0xFFFFu); s[5] += bf2f(v.z >> 16);
        s[6] += bf2f(v.w & 0xFFFFu); s[7] += bf2f(v.w >> 16);
    }
    __shared__ float red[16][128];
    *(float4*)&red[tg][ci8]     = make_float4(s[0], s[1], s[2], s[3]);
    *(float4*)&red[tg][ci8 + 4] = make_float4(s[4], s[5], s[6], s[7]);
    __syncthreads();
    if (tid < 128) {
        float v = 0.f;
        #pragma unroll
        for (int i = 0; i < 16; ++i) v += red[i][tid];
        xt[(size_t)bid * 128 + tid] = v;
    }
}

// Combined small-GEMM kernel: blocks 0..31 -> asum (per b), blocks 32..47 -> tsum (128 rows each).
__global__ __launch_bounds__(256, 2) void sums_kernel(
    const uint16_t* __restrict__ xa16, const float* __restrict__ xt,
    const uint16_t* __restrict__ x16, const uint16_t* __restrict__ wp,
    const float* __restrict__ bias, float* __restrict__ asum, float* __restrict__ tsum)
{
    __shared__ __align__(16) uint16_t slab[130 * 128];   // 33280 B (shared by both paths)
    const int tid = threadIdx.x;
    const int lane = tid & 63, wid = tid >> 6;
    const int wm = wid >> 1, wn = wid & 1;
    const int lr = lane & 15, lg = lane >> 4;
    f32x4 acc[4][4];
    #pragma unroll
    for (int mi = 0; mi < 4; ++mi)
        #pragma unroll
        for (int ni = 0; ni < 4; ++ni) acc[mi][ni] = (f32x4)0.f;

    if (blockIdx.x < 32) {
        // ---- asum[b][t][co] = conv(Xa)[t][co] + 64*bias ----
        const int b = blockIdx.x;
        #pragma unroll
        for (int it = 0; it < 9; ++it) {
            const int gg = it * 256 + tid;
            if (gg < 2080) {
                const int row = gg >> 4, sp = gg & 15;
                const int sl = sp ^ (row & 7);
                *(uint4*)(slab + gg * 8) =
                    *(const uint4*)(xa16 + (size_t)(b * 130 + row) * 128 + sl * 8);
            }
        }
        __syncthreads();
        #pragma unroll
        for (int g = 0; g < 4; ++g)
            #pragma unroll
            for (int d = 0; d < 3; ++d) {
                bf16x8 bq[4], af[4];
                #pragma unroll
                for (int ni = 0; ni < 4; ++ni)
                    bq[ni] = *(const bf16x8*)(wp + (size_t)((((d * 4 + g) * 8) + wn * 4 + ni) * 64 + lane) * 8);
                #pragma unroll
                for (int mi = 0; mi < 4; ++mi) {
                    const int row = wm * 64 + mi * 16 + lr + d;
                    af[mi] = *(const bf16x8*)(slab + row * 128 + ((g * 4 + lg) ^ (row & 7)) * 8);
                }
                #pragma unroll
                for (int mi = 0; mi < 4; ++mi)
                    #pragma unroll
                    for (int ni = 0; ni < 4; ++ni)
                        acc[mi][ni] = __builtin_amdgcn_mfma_f32_16x16x32_bf16(af[mi], bq[ni], acc[mi][ni], 0, 0, 0);
            }
        #pragma unroll
        for (int ni = 0; ni < 4; ++ni) {
            const int col = wn * 64 + ni * 16 + lr;
            const float bv = 64.f * bias[col];
            #pragma unroll
            for (int mi = 0; mi < 4; ++mi)
                #pragma unroll
                for (int j = 0; j < 4; ++j) {
                    const int t = wm * 64 + mi * 16 + lg * 4 + j;
                    asum[((size_t)b * 128 + t) * 128 + col] = acc[mi][ni][j] + bv;
                }
        }
        return;
    }

    // ---- tsum[b][a][co] = sum_d W_d * V_d + 128*bias, V0=S-x127, V1=S, V2=S-x0 ----
    const int bid = blockIdx.x - 32;            // rows bid*128..+127 of (b*64+a)
    const int r = tid >> 1, h = tid & 1;
    const int grow = bid * 128 + r, sb = grow >> 6, sa = grow & 63;
    #pragma unroll
    for (int d = 0; d < 3; ++d) {
        {
            const float* Sp = xt + (size_t)grow * 128 + h * 64;
            const uint16_t* Ep = x16 + ((size_t)(sb * 130 + (d == 0 ? 128 : 1)) * 64 + sa) * 128 + h * 64;
            #pragma unroll
            for (int k = 0; k < 8; ++k) {
                float4 f0 = *(const float4*)(Sp + k * 8);
                float4 f1 = *(const float4*)(Sp + k * 8 + 4);
                if (d != 1) {
                    const uint4 e = *(const uint4*)(Ep + k * 8);
                    f0.x -= bf2f(e.x & 0xFFFFu); f0.y -= bf2f(e.x >> 16);
                    f0.z -= bf2f(e.y & 0xFFFFu); f0.w -= bf2f(e.y >> 16);
                    f1.x -= bf2f(e.z & 0xFFFFu); f1.y -= bf2f(e.z >> 16);
                    f1.z -= bf2f(e.w & 0xFFFFu); f1.w -= bf2f(e.w >> 16);
                }
                uint4 o;
                o.x = pk2(f0.x, f0.y); o.y = pk2(f0.z, f0.w);
                o.z = pk2(f1.x, f1.y); o.w = pk2(f1.z, f1.w);
                const int sl = h * 8 + k;
                *(uint4*)(slab + r * 128 + (sl ^ (r & 7)) * 8) = o;
            }
        }
        __syncthreads();
        #pragma unroll
        for (int g = 0; g < 4; ++g) {
            bf16x8 bq[4], af[4];
            #pragma unroll
            for (int ni = 0; ni < 4; ++ni)
                bq[ni] = *(const bf16x8*)(wp + (size_t)((((d * 4 + g) * 8) + wn * 4 + ni) * 64 + lane) * 8);
            #pragma unroll
            for (int mi = 0; mi < 4; ++mi) {
                const int row = wm * 64 + mi * 16 + lr;
                af[mi] = *(const bf16x8*)(slab + row * 128 + ((g * 4 + lg) ^ (row & 7)) * 8);
            }
            #pragma unroll
            for (int mi = 0; mi < 4; ++mi)
                #pragma unroll
                for (int ni = 0; ni < 4; ++ni)
                    acc[mi][ni] = __builtin_amdgcn_mfma_f32_16x16x32_bf16(af[mi], bq[ni], acc[mi][ni], 0, 0, 0);
        }
        __syncthreads();
    }
    #pragma unroll
    for (int ni = 0; ni < 4; ++ni) {
        const int col = wn * 64 + ni * 16 + lr;
        const float bv = 128.f * bias[col];
        #pragma unroll
        for (int mi = 0; mi < 4; ++mi)
            #pragma unroll
            for (int j = 0; j < 4; ++j) {
                const int rg = bid * 128 + wm * 64 + mi * 16 + lg * 4 + j;
                tsum[(size_t)rg * 128 + col] = acc[mi][ni][j] + bv;
            }
    }
}

// Fused conv + epilogue: one block per (b, t), 512 threads / 8 waves (each a 16-co slice).
// Slab 192 rows x 128 ci bf16 = 48 KB -> 3 blocks/CU.  XCD-swizzled block order.
__global__ __launch_bounds__(512, 6) void conv_kernel(
    const uint16_t* __restrict__ x16, const uint16_t* __restrict__ wp,
    const float* __restrict__ bias, const float* __restrict__ asum,
    const float* __restrict__ tsum, float* __restrict__ out)
{
    __shared__ __align__(16) uint16_t slab[192 * 128];   // 48 KB
    const int tid = threadIdx.x;
    // XCD swizzle: consecutive logical t-blocks land on the same XCD (4096 = 8*512)
    const int raw = blockIdx.x;
    const int bid = (raw & 7) * 512 + (raw >> 3);        // b*128 + t
    const int b = bid >> 7, t = bid & 127;
    const int lane = tid & 63, wid = tid >> 6;           // wid 0..7
    const int lr = lane & 15, lg = lane >> 4;

    // ---- async stage: wave wid stages rows wid*24..+23 (6 gll, 4 rows each) ----
    // LDS dest is WAVE-UNIFORM base; HW adds lane*16B itself (m104/m108).
    // wave chunk = 24 rows * 128 el = 3072 el; per-gll chunk = 4 rows = 512 el.
    #pragma unroll
    for (int k = 0; k < 6; ++k) {
        const int row = wid * 24 + k * 4 + lg;           // 0..191 -> tp = t + row/64
        const int sl = lr ^ (row & 7);                   // logical granule for phys slot lr
        const uint16_t* src = x16 +
            ((size_t)((b * 130 + t + (row >> 6)) * 64 + (row & 63))) * 128 + sl * 8;
        gll16(src, slab + wid * 3072 + k * 512);
    }
    __syncthreads();

    f32x4 acc[4];
    #pragma unroll
    for (int mi = 0; mi < 4; ++mi) acc[mi] = (f32x4)0.f;

    #pragma unroll
    for (int g = 0; g < 4; ++g)
        #pragma unroll
        for (int d = 0; d < 3; ++d) {
            bf16x8 bq, af[4];
            bq = *(const bf16x8*)(wp + (size_t)((((d * 4 + g) * 8) + wid) * 64 + lane) * 8);
            #pragma unroll
            for (int mi = 0; mi < 4; ++mi) {
                const int row = d * 64 + mi * 16 + lr;
                af[mi] = *(const bf16x8*)(slab + row * 128 + ((g * 4 + lg) ^ (row & 7)) * 8);
            }
            #pragma unroll
            for (int mi = 0; mi < 4; ++mi)
                acc[mi] = __builtin_amdgcn_mfma_f32_16x16x32_bf16(af[mi], bq, acc[mi], 0, 0, 0);
        }
    __syncthreads();

    // ---- epilogue A: y = acc + bias -> bf16 bounce into rows 0..63 (t-1 slab, done) ----
    {
        const int col = wid * 16 + lr;
        const float bv = bias[col];
        #pragma unroll
        for (int mi = 0; mi < 4; ++mi)
            #pragma unroll
            for (int j = 0; j < 4; ++j) {
                const int a = mi * 16 + lg * 4 + j;
                slab[a * 128 + (col ^ ((a & 7) << 3))] = (uint16_t)f2bf(acc[mi][j] + bv);
            }
    }
    __syncthreads();

    // ---- epilogue B: out = relu((asum + tsum - y)*inv + x), coalesced (x = slab rows 64..127) ----
    {
        const float inv = 0.07254762501100116f;
        const int cg = tid & 15, rb = tid >> 4;              // rb 0..31
        const float* ap = asum + ((size_t)(b * 128 + t)) * 128 + cg * 8;
        const float4 as0 = *(const float4*)ap, as1 = *(const float4*)(ap + 4);
        const float av[8] = {as0.x, as0.y, as0.z, as0.w, as1.x, as1.y, as1.z, as1.w};
        #pragma unroll
        for (int j = 0; j < 2; ++j) {
            const int a = j * 32 + rb;
            const uint4 yv = *(const uint4*)(slab + a * 128 + ((cg * 8) ^ ((a & 7) << 3)));
            const uint4 xv = *(const uint4*)(slab + (a + 64) * 128 + ((cg * 8) ^ ((a & 7) << 3)));
            const float* tp = tsum + ((size_t)(b * 64 + a)) * 128 + cg * 8;
            const float4 ts0 = *(const float4*)tp, ts1 = *(const float4*)(tp + 4);
            float yy[8], xx[8];
            yy[0] = bf2f(yv.x & 0xFFFFu); yy[1] = bf2f(yv.x >> 16);
            yy[2] = bf2f(yv.y & 0xFFFFu); yy[3] = bf2f(yv.y >> 16);
            yy[4] = bf2f(yv.z & 0xFFFFu); yy[5] = bf2f(yv.z >> 16);
            yy[6] = bf2f(yv.w & 0xFFFFu); yy[7] = bf2f(yv.w >> 16);
            xx[0] = bf2f(xv.x & 0xFFFFu); xx[1] = bf2f(xv.x >> 16);
            xx[2] = bf2f(xv.y & 0xFFFFu); xx[3] = bf2f(xv.y >> 16);
            xx[4] = bf2f(xv.z & 0xFFFFu); xx[5] = bf2f(xv.z >> 16);
            xx[6] = bf2f(xv.w & 0xFFFFu); xx[7] = bf2f(xv.w >> 16);
            const float tv[8] = {ts0.x, ts0.y, ts0.z, ts0.w, ts1.x, ts1.y, ts1.z, ts1.w};
            float o[8];
            #pragma unroll
            for (int i = 0; i < 8; ++i) {
                const float gg = (av[i] + tv[i] - yy[i]) * inv + xx[i];
                o[i] = gg > 0.f ? gg : 0.f;
            }
            float* op = out + ((size_t)((b * 128 + t) * 64 + a)) * 128 + cg * 8;
            *(float4*)op       = make_float4(o[0], o[1], o[2], o[3]);
            *(float4*)(op + 4) = make_float4(o[4], o[5], o[6], o[7]);
        }
    }
}

extern "C" void kernel_launch(void* const* d_in, const int* in_sizes, int n_in,
                              void* d_out, int out_size, void* d_ws, size_t ws_size,
                              hipStream_t stream) {
    const float* x    = (const float*)d_in[0];
    const float* W    = (const float*)d_in[1];
    const float* bias = (const float*)d_in[2];
    float* out = (float*)d_out;

    // ws layout (73.5 MB):
    //   x16  [32][130][64][128] bf16 : 68,157,440
    //   wp   49152 bf16              :     98,304
    //   xa16 [32][130][128] bf16     :  1,064,960
    //   xt   [32][64][128] f32       :  1,048,576
    //   asum [32][128][128] f32      :  2,097,152
    //   tsum [32][64][128] f32       :  1,048,576
    char* ws = (char*)d_ws;
    uint16_t* x16  = (uint16_t*)(ws);
    uint16_t* wp   = (uint16_t*)(ws + 68157440);
    uint16_t* xa16 = (uint16_t*)(ws + 68157440 + 98304);
    float* xt      = (float*)(ws + 68157440 + 98304 + 1064960);
    float* asum    = (float*)(ws + 68157440 + 98304 + 1064960 + 1048576);
    float* tsum    = (float*)(ws + 68157440 + 98304 + 1064960 + 1048576 + 2097152);

    prep_kernel <<<4352, 256, 0, stream>>>(x, x16, xa16, W, wp);   // prep + fused wpack
    xt_kernel   <<<2048, 256, 0, stream>>>(x16, xt);
    sums_kernel <<<48,   256, 0, stream>>>(xa16, xt, x16, wp, bias, asum, tsum);
    conv_kernel <<<4096, 512, 0, stream>>>(x16, wp, bias, asum, tsum, out);
}

// Round 9
// 115.665 us; speedup vs baseline: 1.2344x; 1.0178x over previous
//
#include <hip/hip_runtime.h>
#include <stdint.h>

// B=32, L=128, A=64, C=128, KT=3.  scale = sqrt(190), inv = 1/sqrt(190).
// Linearity: agent_sum(y) = conv(sum_a x) + 64*bias ; time_sum(y) = W0*(S-x127)+W1*S+W2*(S-x0)+128*bias.
// Main conv fuses the whole epilogue and writes out directly (y never materialized).

typedef __attribute__((ext_vector_type(8))) short bf16x8;
typedef __attribute__((ext_vector_type(4))) float f32x4;

__device__ __forceinline__ uint32_t f2bf(float f) {
    union { float f; uint32_t u; } v; v.f = f;
    return (v.u + 0x7FFFu + ((v.u >> 16) & 1u)) >> 16;  // RNE
}
__device__ __forceinline__ float bf2f(uint32_t h) {
    union { uint32_t u; float f; } v; v.u = h << 16; return v.f;
}
__device__ __forceinline__ uint32_t pk2(float lo, float hi) {
    return f2bf(lo) | (f2bf(hi) << 16);
}
__device__ __forceinline__ void gll16(const void* g, void* l) {
    __builtin_amdgcn_global_load_lds((const __attribute__((address_space(1))) void*)g,
                                     (__attribute__((address_space(3))) void*)l, 16, 0, 0);
}

// prep: x fp32 [b][t][a][c] -> x16 bf16 [b][tp=t+1][a][c] (zero guards tp=0,129) + xa16 = bf16(sum_a x).
// Blocks >= 4160 instead pack W: Wpack[((d*4+ks)*8 + nt)*64 + lane][i],
//   ci = ks*32+(lane>>4)*8+i, co = nt*16+(lane&15)
__global__ __launch_bounds__(256) void prep_kernel(
    const float* __restrict__ x, uint16_t* __restrict__ x16, uint16_t* __restrict__ xa16,
    const float* __restrict__ W, uint16_t* __restrict__ wp)
{
    const int tid = threadIdx.x;
    const int bid = blockIdx.x;
    if (bid >= 4160) {                       // wpack: 192 blocks
        int o = (bid - 4160) * 256 + tid;    // 49152 exact
        int i = o & 7, lane = (o >> 3) & 63, nt = (o >> 9) & 7, ks = (o >> 12) & 3, d = o >> 14;
        int ci = ks * 32 + (lane >> 4) * 8 + i;
        int co = nt * 16 + (lane & 15);
        wp[o] = (uint16_t)f2bf(W[(co * 128 + ci) * 3 + d]);
        return;
    }
    const int b = bid / 130, tp = bid - b * 130;   // b*130 + tp
    uint16_t* xo = x16 + (size_t)bid * 8192;
    if (tp == 0 || tp == 129) {
        const uint4 z = make_uint4(0, 0, 0, 0);
        #pragma unroll
        for (int k = 0; k < 4; ++k) *(uint4*)(xo + tid * 32 + k * 8) = z;
        if (tid < 16) *(uint4*)(xa16 + (size_t)bid * 128 + tid * 8) = z;
        return;
    }
    const int t = tp - 1;
    const int ci8 = (tid & 15) * 8, ag = tid >> 4;      // 16 a-groups x 4 rows
    const float* xr = x + (size_t)(b * 128 + t) * 8192;
    float s[8];
    #pragma unroll
    for (int j = 0; j < 8; ++j) s[j] = 0.f;
    #pragma unroll
    for (int r = 0; r < 4; ++r) {
        const int a = ag * 4 + r;
        const float4 v0 = *(const float4*)(xr + a * 128 + ci8);
        const float4 v1 = *(const float4*)(xr + a * 128 + ci8 + 4);
        s[0] += v0.x; s[1] += v0.y; s[2] += v0.z; s[3] += v0.w;
        s[4] += v1.x; s[5] += v1.y; s[6] += v1.z; s[7] += v1.w;
        uint4 p;
        p.x = pk2(v0.x, v0.y); p.y = pk2(v0.z, v0.w);
        p.z = pk2(v1.x, v1.y); p.w = pk2(v1.z, v1.w);
        *(uint4*)(xo + a * 128 + ci8) = p;
    }
    __shared__ float red[16][128];
    *(float4*)&red[ag][ci8]     = make_float4(s[0], s[1], s[2], s[3]);
    *(float4*)&red[ag][ci8 + 4] = make_float4(s[4], s[5], s[6], s[7]);
    __syncthreads();
    if (tid < 128) {
        float v = 0.f;
        #pragma unroll
        for (int i = 0; i < 16; ++i) v += red[i][tid];
        xa16[(size_t)bid * 128 + tid] = (uint16_t)f2bf(v);
    }
}

// Xt[b][a][ci] = sum_t x (fp32), read from x16 (L2/L3-hot)
__global__ __launch_bounds__(256) void xt_kernel(
    const uint16_t* __restrict__ x16, float* __restrict__ xt)
{
    const int tid = threadIdx.x, bid = blockIdx.x;   // b*64 + a
    const int a = bid & 63, b = bid >> 6;
    const int ci8 = (tid & 15) * 8, tg = tid >> 4;
    const uint16_t* base = x16 + ((size_t)(b * 130 + 1 + tg) * 64 + a) * 128 + ci8;
    float s[8];
    #pragma unroll
    for (int j = 0; j < 8; ++j) s[j] = 0.f;
    #pragma unroll
    for (int r = 0; r < 8; ++r) {
        const uint4 v = *(const uint4*)(base + (size_t)r * 16 * 8192);
        s[0] += bf2f(v.x & 0xFFFFu); s[1] += bf2f(v.x >> 16);
        s[2] += bf2f(v.y & 0xFFFFu); s[3] += bf2f(v.y >> 16);
        s[4] += bf2f(v.z & 0xFFFFu); s[5] += bf2f(v.z >> 16);
        s[6] += bf2f(v.w & 0xFFFFu); s[7] += bf2f(v.w >> 16);
    }
    __shared__ float red[16][128];
    *(float4*)&red[tg][ci8]     = make_float4(s[0], s[1], s[2], s[3]);
    *(float4*)&red[tg][ci8 + 4] = make_float4(s[4], s[5], s[6], s[7]);
    __syncthreads();
    if (tid < 128) {
        float v = 0.f;
        #pragma unroll
        for (int i = 0; i < 16; ++i) v += red[i][tid];
        xt[(size_t)bid * 128 + tid] = v;
    }
}

// Combined small-GEMM kernel: blocks 0..31 -> asum (per b), blocks 32..47 -> tsum (128 rows each).
__global__ __launch_bounds__(256, 2) void sums_kernel(
    const uint16_t* __restrict__ xa16, const float* __restrict__ xt,
    const uint16_t* __restrict__ x16, const uint16_t* __restrict__ wp,
    const float* __restrict__ bias, float* __restrict__ asum, float* __restrict__ tsum)
{
    __shared__ __align__(16) uint16_t slab[130 * 128];   // 33280 B (shared by both paths)
    const int tid = threadIdx.x;
    const int lane = tid & 63, wid = tid >> 6;
    const int wm = wid >> 1, wn = wid & 1;
    const int lr = lane & 15, lg = lane >> 4;
    f32x4 acc[4][4];
    #pragma unroll
    for (int mi = 0; mi < 4; ++mi)
        #pragma unroll
        for (int ni = 0; ni < 4; ++ni) acc[mi][ni] = (f32x4)0.f;

    if (blockIdx.x < 32) {
        // ---- asum[b][t][co] = conv(Xa)[t][co] + 64*bias ----
        const int b = blockIdx.x;
        #pragma unroll
        for (int it = 0; it < 9; ++it) {
            const int gg = it * 256 + tid;
            if (gg < 2080) {
                const int row = gg >> 4, sp = gg & 15;
                const int sl = sp ^ (row & 7);
                *(uint4*)(slab + gg * 8) =
                    *(const uint4*)(xa16 + (size_t)(b * 130 + row) * 128 + sl * 8);
            }
        }
        __syncthreads();
        #pragma unroll
        for (int g = 0; g < 4; ++g)
            #pragma unroll
            for (int d = 0; d < 3; ++d) {
                bf16x8 bq[4], af[4];
                #pragma unroll
                for (int ni = 0; ni < 4; ++ni)
                    bq[ni] = *(const bf16x8*)(wp + (size_t)((((d * 4 + g) * 8) + wn * 4 + ni) * 64 + lane) * 8);
                #pragma unroll
                for (int mi = 0; mi < 4; ++mi) {
                    const int row = wm * 64 + mi * 16 + lr + d;
                    af[mi] = *(const bf16x8*)(slab + row * 128 + ((g * 4 + lg) ^ (row & 7)) * 8);
                }
                #pragma unroll
                for (int mi = 0; mi < 4; ++mi)
                    #pragma unroll
                    for (int ni = 0; ni < 4; ++ni)
                        acc[mi][ni] = __builtin_amdgcn_mfma_f32_16x16x32_bf16(af[mi], bq[ni], acc[mi][ni], 0, 0, 0);
            }
        #pragma unroll
        for (int ni = 0; ni < 4; ++ni) {
            const int col = wn * 64 + ni * 16 + lr;
            const float bv = 64.f * bias[col];
            #pragma unroll
            for (int mi = 0; mi < 4; ++mi)
                #pragma unroll
                for (int j = 0; j < 4; ++j) {
                    const int t = wm * 64 + mi * 16 + lg * 4 + j;
                    asum[((size_t)b * 128 + t) * 128 + col] = acc[mi][ni][j] + bv;
                }
        }
        return;
    }

    // ---- tsum[b][a][co] = sum_d W_d * V_d + 128*bias, V0=S-x127, V1=S, V2=S-x0 ----
    const int bid = blockIdx.x - 32;            // rows bid*128..+127 of (b*64+a)
    const int r = tid >> 1, h = tid & 1;
    const int grow = bid * 128 + r, sb = grow >> 6, sa = grow & 63;
    #pragma unroll
    for (int d = 0; d < 3; ++d) {
        {
            const float* Sp = xt + (size_t)grow * 128 + h * 64;
            const uint16_t* Ep = x16 + ((size_t)(sb * 130 + (d == 0 ? 128 : 1)) * 64 + sa) * 128 + h * 64;
            #pragma unroll
            for (int k = 0; k < 8; ++k) {
                float4 f0 = *(const float4*)(Sp + k * 8);
                float4 f1 = *(const float4*)(Sp + k * 8 + 4);
                if (d != 1) {
                    const uint4 e = *(const uint4*)(Ep + k * 8);
                    f0.x -= bf2f(e.x & 0xFFFFu); f0.y -= bf2f(e.x >> 16);
                    f0.z -= bf2f(e.y & 0xFFFFu); f0.w -= bf2f(e.y >> 16);
                    f1.x -= bf2f(e.z & 0xFFFFu); f1.y -= bf2f(e.z >> 16);
                    f1.z -= bf2f(e.w & 0xFFFFu); f1.w -= bf2f(e.w >> 16);
                }
                uint4 o;
                o.x = pk2(f0.x, f0.y); o.y = pk2(f0.z, f0.w);
                o.z = pk2(f1.x, f1.y); o.w = pk2(f1.z, f1.w);
                const int sl = h * 8 + k;
                *(uint4*)(slab + r * 128 + (sl ^ (r & 7)) * 8) = o;
            }
        }
        __syncthreads();
        #pragma unroll
        for (int g = 0; g < 4; ++g) {
            bf16x8 bq[4], af[4];
            #pragma unroll
            for (int ni = 0; ni < 4; ++ni)
                bq[ni] = *(const bf16x8*)(wp + (size_t)((((d * 4 + g) * 8) + wn * 4 + ni) * 64 + lane) * 8);
            #pragma unroll
            for (int mi = 0; mi < 4; ++mi) {
                const int row = wm * 64 + mi * 16 + lr;
                af[mi] = *(const bf16x8*)(slab + row * 128 + ((g * 4 + lg) ^ (row & 7)) * 8);
            }
            #pragma unroll
            for (int mi = 0; mi < 4; ++mi)
                #pragma unroll
                for (int ni = 0; ni < 4; ++ni)
                    acc[mi][ni] = __builtin_amdgcn_mfma_f32_16x16x32_bf16(af[mi], bq[ni], acc[mi][ni], 0, 0, 0);
        }
        __syncthreads();
    }
    #pragma unroll
    for (int ni = 0; ni < 4; ++ni) {
        const int col = wn * 64 + ni * 16 + lr;
        const float bv = 128.f * bias[col];
        #pragma unroll
        for (int mi = 0; mi < 4; ++mi)
            #pragma unroll
            for (int j = 0; j < 4; ++j) {
                const int rg = bid * 128 + wm * 64 + mi * 16 + lg * 4 + j;
                tsum[(size_t)rg * 128 + col] = acc[mi][ni][j] + bv;
            }
    }
}

// Fused conv + epilogue: one block per (b, t), 512 threads / 8 waves (each a 16-co slice).
// Slab 192 rows x 64 ci bf16 = 24 KB, TWO ci-phases -> 4 blocks/CU (32 waves = HW max).
__global__ __launch_bounds__(512, 8) void conv_kernel(
    const uint16_t* __restrict__ x16, const uint16_t* __restrict__ wp,
    const float* __restrict__ bias, const float* __restrict__ asum,
    const float* __restrict__ tsum, float* __restrict__ out)
{
    __shared__ __align__(16) uint16_t slab[192 * 64];    // 24 KB
    const int tid = threadIdx.x;
    // XCD swizzle: consecutive logical t-blocks land on the same XCD (4096 = 8*512)
    const int raw = blockIdx.x;
    const int bid = (raw & 7) * 512 + (raw >> 3);        // b*128 + t
    const int b = bid >> 7, t = bid & 127;
    const int lane = tid & 63, wid = tid >> 6;           // wid 0..7
    const int lr = lane & 15, lg = lane >> 4;

    f32x4 acc[4];
    #pragma unroll
    for (int mi = 0; mi < 4; ++mi) acc[mi] = (f32x4)0.f;

    // stage chunk c: 192 rows x 64 ci; wave stages 24 rows (3 gll of 8 rows each).
    // LDS dest is WAVE-UNIFORM; HW adds lane*16B.  Row = 128B -> 8 rows per gll.
#define STAGE(c) do {                                                          \
    _Pragma("unroll")                                                          \
    for (int k = 0; k < 3; ++k) {                                              \
        const int row = wid * 24 + k * 8 + (lane >> 3);                        \
        const int gran = (lane & 7) ^ (row & 7);                               \
        const uint16_t* src = x16 +                                            \
            ((size_t)((b * 130 + t + (row >> 6)) * 64 + (row & 63))) * 128 +   \
            (c) * 64 + gran * 8;                                               \
        gll16(src, slab + wid * 1536 + k * 512);                               \
    } } while (0)

#define MFMA_CHUNK(c) do {                                                     \
    _Pragma("unroll")                                                          \
    for (int d = 0; d < 3; ++d)                                                \
        _Pragma("unroll")                                                      \
        for (int g2 = 0; g2 < 2; ++g2) {                                       \
            const int ks = (c) * 2 + g2;                                       \
            bf16x8 bq, af[4];                                                  \
            bq = *(const bf16x8*)(wp +                                         \
                (size_t)((((d * 4 + ks) * 8) + wid) * 64 + lane) * 8);         \
            _Pragma("unroll")                                                  \
            for (int mi = 0; mi < 4; ++mi) {                                   \
                const int row = d * 64 + mi * 16 + lr;                         \
                af[mi] = *(const bf16x8*)(slab + row * 64 +                    \
                    (((g2 * 4 + lg) ^ (row & 7)) * 8));                        \
            }                                                                  \
            _Pragma("unroll")                                                  \
            for (int mi = 0; mi < 4; ++mi)                                     \
                acc[mi] = __builtin_amdgcn_mfma_f32_16x16x32_bf16(             \
                    af[mi], bq, acc[mi], 0, 0, 0);                             \
        } } while (0)

    STAGE(0);
    __syncthreads();
    MFMA_CHUNK(0);
    __syncthreads();          // all chunk0 reads done before overwrite
    STAGE(1);
    __syncthreads();
    MFMA_CHUNK(1);
    __syncthreads();          // all chunk1 reads done before bounce

#undef STAGE
#undef MFMA_CHUNK

    // ---- epilogue A: y = acc + bias -> bf16 bounce.  Center rows 64..127 (ci-hi x)
    // preserved; y goes to rows 0..63 (ci-lo) and 128..191 (ci-hi). ----
    {
        const int col = wid * 16 + lr;                   // co 0..127
        const float bv = bias[col];
        const int cl = col & 63;                         // col within 64-wide row
        const int rbase = (col >> 6) << 7;               // 0 or 128
        #pragma unroll
        for (int mi = 0; mi < 4; ++mi)
            #pragma unroll
            for (int j = 0; j < 4; ++j) {
                const int a = mi * 16 + lg * 4 + j;
                slab[(rbase + a) * 64 + (cl ^ ((a & 7) << 3))] = (uint16_t)f2bf(acc[mi][j] + bv);
            }
    }
    __syncthreads();

    // ---- epilogue B: out = relu((asum + tsum - y)*inv + x) ----
    // y: slab rows [a] (ci-lo) / [128+a] (ci-hi).  x: ci-hi from slab rows [64+a],
    // ci-lo re-read from x16 (L2-hot, 8 KB/block).
    {
        const float inv = 0.07254762501100116f;
        const int cg = tid & 15, rb = tid >> 4;              // rb 0..31
        const float* ap = asum + ((size_t)(b * 128 + t)) * 128 + cg * 8;
        const float4 as0 = *(const float4*)ap, as1 = *(const float4*)(ap + 4);
        const float av[8] = {as0.x, as0.y, as0.z, as0.w, as1.x, as1.y, as1.z, as1.w};
        const int cl8 = (cg & 7) * 8;                        // ci within 64-chunk
        #pragma unroll
        for (int j = 0; j < 2; ++j) {
            const int a = j * 32 + rb;
            const int swz = cl8 ^ ((a & 7) << 3);
            uint4 yv, xv;
            if (cg < 8) {
                yv = *(const uint4*)(slab + a * 64 + swz);
                xv = *(const uint4*)(x16 + ((size_t)((b * 130 + t + 1) * 64 + a)) * 128 + cg * 8);
            } else {
                yv = *(const uint4*)(slab + (128 + a) * 64 + swz);
                xv = *(const uint4*)(slab + (64 + a) * 64 + swz);
            }
            const float* tp = tsum + ((size_t)(b * 64 + a)) * 128 + cg * 8;
            const float4 ts0 = *(const float4*)tp, ts1 = *(const float4*)(tp + 4);
            float yy[8], xx[8];
            yy[0] = bf2f(yv.x & 0xFFFFu); yy[1] = bf2f(yv.x >> 16);
            yy[2] = bf2f(yv.y & 0xFFFFu); yy[3] = bf2f(yv.y >> 16);
            yy[4] = bf2f(yv.z & 0xFFFFu); yy[5] = bf2f(yv.z >> 16);
            yy[6] = bf2f(yv.w & 0xFFFFu); yy[7] = bf2f(yv.w >> 16);
            xx[0] = bf2f(xv.x & 0xFFFFu); xx[1] = bf2f(xv.x >> 16);
            xx[2] = bf2f(xv.y & 0xFFFFu); xx[3] = bf2f(xv.y >> 16);
            xx[4] = bf2f(xv.z & 0xFFFFu); xx[5] = bf2f(xv.z >> 16);
            xx[6] = bf2f(xv.w & 0xFFFFu); xx[7] = bf2f(xv.w >> 16);
            const float tv[8] = {ts0.x, ts0.y, ts0.z, ts0.w, ts1.x, ts1.y, ts1.z, ts1.w};
            float o[8];
            #pragma unroll
            for (int i = 0; i < 8; ++i) {
                const float gg = (av[i] + tv[i] - yy[i]) * inv + xx[i];
                o[i] = gg > 0.f ? gg : 0.f;
            }
            float* op = out + ((size_t)((b * 128 + t) * 64 + a)) * 128 + cg * 8;
            *(float4*)op       = make_float4(o[0], o[1], o[2], o[3]);
            *(float4*)(op + 4) = make_float4(o[4], o[5], o[6], o[7]);
        }
    }
}

extern "C" void kernel_launch(void* const* d_in, const int* in_sizes, int n_in,
                              void* d_out, int out_size, void* d_ws, size_t ws_size,
                              hipStream_t stream) {
    const float* x    = (const float*)d_in[0];
    const float* W    = (const float*)d_in[1];
    const float* bias = (const float*)d_in[2];
    float* out = (float*)d_out;

    // ws layout (73.5 MB):
    //   x16  [32][130][64][128] bf16 : 68,157,440
    //   wp   49152 bf16              :     98,304
    //   xa16 [32][130][128] bf16     :  1,064,960
    //   xt   [32][64][128] f32       :  1,048,576
    //   asum [32][128][128] f32      :  2,097,152
    //   tsum [32][64][128] f32       :  1,048,576
    char* ws = (char*)d_ws;
    uint16_t* x16  = (uint16_t*)(ws);
    uint16_t* wp   = (uint16_t*)(ws + 68157440);
    uint16_t* xa16 = (uint16_t*)(ws + 68157440 + 98304);
    float* xt      = (float*)(ws + 68157440 + 98304 + 1064960);
    float* asum    = (float*)(ws + 68157440 + 98304 + 1064960 + 1048576);
    float* tsum    = (float*)(ws + 68157440 + 98304 + 1064960 + 1048576 + 2097152);

    prep_kernel <<<4352, 256, 0, stream>>>(x, x16, xa16, W, wp);   // prep + fused wpack
    xt_kernel   <<<2048, 256, 0, stream>>>(x16, xt);
    sums_kernel <<<48,   256, 0, stream>>>(xa16, xt, x16, wp, bias, asum, tsum);
    conv_kernel <<<4096, 512, 0, stream>>>(x16, wp, bias, asum, tsum, out);
}